// Round 5
// baseline (616.895 us; speedup 1.0000x reference)
//
#include <hip/hip_runtime.h>
#include <hip/hip_bf16.h>
#include <hip/hip_cooperative_groups.h>
#include <cstdint>

namespace cg = cooperative_groups;

#define NV 100000
#define NE 1600000
#define KIN 128
#define NH 4
#define NC 16
#define NF 64      // NH*NC
#define NBKT 1563  // ceil(NV/64) buckets of 64 dsts
#define BCAP 1216  // mean fill 1024, sd ~32 -> +6 sigma safe (fixed dataset)
#define EPW 16     // edges per thread in bin body (256 thr -> 4096 edges/item)
#define BINWG 391  // ceil(NE / (256*EPW))
#define GEMMWG 1563 // ceil(NV/64), 64 rows per gemm item
#define NITEMS 1954 // BINWG + GEMMWG, interleaved %5
#define XSTR 136   // LDS row stride in bf16 (272 B: b128-aligned, bank-uniform)

typedef __attribute__((ext_vector_type(8))) short bf16x8;
typedef __attribute__((ext_vector_type(4))) float f32x4;

__device__ __forceinline__ short f2bf(float f) {   // RNE bf16
    unsigned u = __float_as_uint(f);
    return (short)((u + 0x7FFFu + ((u >> 16) & 1u)) >> 16);
}

// 11-bit positive-float weight codec: e5m6, bias field 7168=(112<<6).
// Covers w in [2^-15, 2^16]; rel err <= 2^-7 RNE.
__device__ __forceinline__ unsigned enc11(float w) {
    unsigned t = (__float_as_uint(w) + 0x10000u) >> 17;
    t = min(max(t, 7168u), 9215u);
    return t - 7168u;
}

// ONE cooperative kernel: P0 prep -> sync -> P1 front (bin+gemm) -> sync ->
// P2 back. Round-4 lesson: dur ~= kernel + 19us (vs +75us for 3 kernels),
// so fusion is right — but joint regalloc hit 84 VGPR -> 4 blk/CU -> half
// the waves -> 4x slowdown. Fix: __launch_bounds__(256,8) caps VGPR at 64
// (each standalone phase needed <=36), restoring 8 blk/CU so the grid holds
// all NITEMS blocks co-resident: P1/P2 then match their standalone shapes.
__global__ __launch_bounds__(256, 8) void k_fused(
    const float* __restrict__ x, const int* __restrict__ ei,
    const float* __restrict__ W, const float* __restrict__ a_src,
    const float* __restrict__ a_dst,
    __hip_bfloat16* __restrict__ z, float* __restrict__ esrc,
    float* __restrict__ edst, int* __restrict__ gcur,
    short* __restrict__ wfrag, unsigned* __restrict__ barr,
    float* __restrict__ out)
{
    __shared__ __align__(16) union SM {
        struct { int hist[NBKT]; int base[NBKT]; } bin;            // 12504 B
        short xs[64 * XSTR];                                       // 17408 B
        struct {
            unsigned arr[BCAP];            // 4864
            unsigned long long rec[BCAP];  // 9728
            int hist[64], off[64], cur[64];
            float4 led[64];                // -> total 16384 B
        } back;
    } sm;

    cg::grid_group grid = cg::this_grid();
    const int t = threadIdx.x;
    const int bid = blockIdx.x;
    const int gsz = gridDim.x;
    const int gtid = bid * 256 + t;
    const int gth = gsz * 256;

    // ---------------- P0: zero gcur, build wfrag ----------------
    for (int i = gtid; i < NBKT; i += gth) gcur[i] = 0;
    for (int g = gtid; g < 1280; g += gth) {
        const int lane = g & 63;
        const int ctks = g >> 6;               // 0..19
        const int ct = ctks >> 2, ks = ctks & 3;
        const int n = lane & 15, quad = lane >> 4;
        short* dst = wfrag + (size_t)g * 8;
#pragma unroll
        for (int j = 0; j < 8; ++j) {
            const int k = ks * 32 + quad * 8 + j;
            float v = 0.f;
            if (ct < 4) {
                v = W[k * NF + ct * 16 + n];
            } else if (n < 8) {
                const int h = n & 3;
                const float* __restrict__ a =
                    (n < 4) ? (a_src + h * 16) : (a_dst + h * 16);
                for (int c = 0; c < 16; ++c)
                    v += W[k * NF + h * 16 + c] * a[c];
            }
            dst[j] = f2bf(v);
        }
    }
    __threadfence();
    grid.sync();

    // ---------------- P1: edge binning + MFMA gemm ----------------
    for (int it = bid; it < NITEMS; it += gsz) {
        __syncthreads();   // LDS union reuse across items
        if (it % 5 == 0) {
            // ---- bin item: bucket edges by dst>>6, item=(dlocal<<17)|src ----
            int* hist = sm.bin.hist;
            int* base = sm.bin.base;
            const int e0 = (it / 5) * (256 * EPW);

            for (int i = t; i < NBKT; i += 256) hist[i] = 0;
            __syncthreads();

            unsigned pk[EPW];
            short bk[EPW];
#pragma unroll
            for (int i = 0; i < EPW; ++i) {
                const int e = e0 + i * 256 + t;
                if (e < NE) {
                    const int s = ei[e];
                    const int d = ei[NE + e];
                    const int bkt = d >> 6;
                    bk[i] = (short)bkt;
                    pk[i] = ((unsigned)(d & 63) << 17) | (unsigned)s;
                    atomicAdd(&hist[bkt], 1);
                } else {
                    bk[i] = -1;
                }
            }
            __syncthreads();
            for (int i = t; i < NBKT; i += 256) {
                const int c = hist[i];
                base[i] = c ? atomicAdd(&gcur[i], c) : 0;
                hist[i] = 0;   // reuse as local cursor
            }
            __syncthreads();
#pragma unroll
            for (int i = 0; i < EPW; ++i) {
                if (bk[i] >= 0) {
                    const int bkt = bk[i];
                    const int pos = base[bkt] + atomicAdd(&hist[bkt], 1);
                    if (pos < BCAP)
                        barr[(size_t)bkt * BCAP + pos] = pk[i];
                }
            }
        } else {
            // ---- gemm item: [z | logits] = x @ [W | Wa], 64 rows ----
            short* xs = sm.xs;
            const int idg = it - it / 5 - 1;   // 0..GEMMWG-1
            const float4* __restrict__ x4 = (const float4*)x;

#pragma unroll
            for (int i = 0; i < 8; ++i) {
                const int li = i * 256 + t;
                const int idx = idg * 2048 + li;
                float4 v = make_float4(0.f, 0.f, 0.f, 0.f);
                if (idx < NV * (KIN / 4)) v = x4[idx];
                const unsigned lo = (unsigned)(unsigned short)f2bf(v.x)
                                  | ((unsigned)(unsigned short)f2bf(v.y) << 16);
                const unsigned hi = (unsigned)(unsigned short)f2bf(v.z)
                                  | ((unsigned)(unsigned short)f2bf(v.w) << 16);
                *(uint2*)&xs[(li >> 5) * XSTR + (li & 31) * 4] =
                    make_uint2(lo, hi);
            }
            __syncthreads();

            const int wv = t >> 6;
            const int lane = t & 63;
            const int n = lane & 15;
            const int quad = lane >> 4;

            const bf16x8* __restrict__ wf = (const bf16x8*)wfrag;
            const short* __restrict__ arow = &xs[(wv * 16 + n) * XSTR];
            f32x4 acc[5];
#pragma unroll
            for (int ct = 0; ct < 5; ++ct) acc[ct] = (f32x4){0.f, 0.f, 0.f, 0.f};

#pragma unroll
            for (int ks = 0; ks < 4; ++ks) {
                const bf16x8 af = *(const bf16x8*)(arow + ks * 32 + quad * 8);
#pragma unroll
                for (int ct = 0; ct < 5; ++ct)
                    acc[ct] = __builtin_amdgcn_mfma_f32_16x16x32_bf16(
                        af, wf[(ct * 4 + ks) * 64 + lane], acc[ct], 0, 0, 0);
            }

            unsigned short* __restrict__ zz = (unsigned short*)z;
#pragma unroll
            for (int ct = 0; ct < 4; ++ct) {
#pragma unroll
                for (int reg = 0; reg < 4; ++reg) {
                    const int r_g = idg * 64 + wv * 16 + quad * 4 + reg;
                    if (r_g < NV)
                        zz[(size_t)r_g * NF + ct * 16 + n] =
                            (unsigned short)f2bf(acc[ct][reg]);
                }
            }
#pragma unroll
            for (int reg = 0; reg < 4; ++reg) {
                const int r_g = idg * 64 + wv * 16 + quad * 4 + reg;
                if (r_g < NV && n < 8) {
                    const float v = acc[4][reg];
                    if (n < 4) esrc[r_g * NH + n] = v;
                    else       edst[r_g * NH + (n - 4)] = v;
                }
            }
        }
    }
    __threadfence();
    grid.sync();

    // ---------------- P2: fused CSR-build + aggregation ----------------
    for (int b = bid; b < NBKT; b += gsz) {
        __syncthreads();   // LDS union reuse across buckets
        auto& B = sm.back;
        int f = gcur[b]; if (f > BCAP) f = BCAP;
        const unsigned* __restrict__ bp = barr + (size_t)b * BCAP;

        if (t < 64) {
            B.hist[t] = 0;
            B.cur[t] = 0;
            const int d = b * 64 + t;
            B.led[t] = (d < NV) ? *(const float4*)(edst + (size_t)d * 4)
                                : make_float4(0.f, 0.f, 0.f, 0.f);
        }
        __syncthreads();
        const int f4 = f >> 2;
        for (int i = t; i < f4; i += 256) {
            const uint4 v = ((const uint4*)bp)[i];
            ((uint4*)B.arr)[i] = v;
            atomicAdd(&B.hist[v.x >> 17], 1);
            atomicAdd(&B.hist[v.y >> 17], 1);
            atomicAdd(&B.hist[v.z >> 17], 1);
            atomicAdd(&B.hist[v.w >> 17], 1);
        }
        for (int i = (f4 << 2) + t; i < f; i += 256) {
            const unsigned v = bp[i];
            B.arr[i] = v;
            atomicAdd(&B.hist[v >> 17], 1);
        }
        __syncthreads();
        if (t < 64) B.off[t] = B.hist[t];
        __syncthreads();
        for (int s = 1; s < 64; s <<= 1) {
            const int v = (t < 64 && t >= s) ? B.off[t - s] : 0;
            __syncthreads();
            if (t < 64) B.off[t] += v;
            __syncthreads();
        }
        if (t < 64) B.off[t] -= B.hist[t];   // exclusive
        __syncthreads();

        // build sorted weight records in LDS
        for (int i = t; i < f; i += 256) {
            const unsigned p = B.arr[i];
            const int dl = p >> 17;
            const unsigned s = p & 0x1FFFFu;
            const int slot = B.off[dl] + atomicAdd(&B.cur[dl], 1);
            const float4 e4 = *(const float4*)(esrc + (size_t)s * 4);
            const float4 ed = B.led[dl];
            float ev;
            ev = e4.x + ed.x; ev = ev > 0.f ? ev : 0.2f * ev;
            const unsigned w0 = enc11(__expf(ev));
            ev = e4.y + ed.y; ev = ev > 0.f ? ev : 0.2f * ev;
            const unsigned w1 = enc11(__expf(ev));
            ev = e4.z + ed.z; ev = ev > 0.f ? ev : 0.2f * ev;
            const unsigned w2 = enc11(__expf(ev));
            ev = e4.w + ed.w; ev = ev > 0.f ? ev : 0.2f * ev;
            const unsigned w3 = enc11(__expf(ev));
            B.rec[slot] = (unsigned long long)s
                | ((unsigned long long)w0 << 17)
                | ((unsigned long long)w1 << 28)
                | ((unsigned long long)w2 << 39)
                | ((unsigned long long)w3 << 50);
        }
        __syncthreads();

        // aggregation: wave wv handles dls with (dl&3)==wv; 8 edges per iter
        const int wv = t >> 6;
        const int lane = t & 63;
        const int quad = lane >> 4;          // edge slot within group
        const int li = lane & 15;            // channel-quad: chans 4li..4li+3
        const int sh = 17 + 11 * (li >> 2);  // this lane's head weight field
        const unsigned short* __restrict__ zb =
            (const unsigned short*)z + li * 4;

        for (int k = 0; k < 16; ++k) {
            const int dl = (k << 2) | wv;
            const int d = b * 64 + dl;
            const int begin = B.off[dl];
            const int nd = B.hist[dl];
            float a0 = 0.f, a1 = 0.f, a2 = 0.f, a3 = 0.f, den = 0.f;
            for (int j = 0; j < nd; j += 8) {
                const int je0 = j + quad;
                const int je1 = je0 + 4;
                const unsigned long long r0 = (je0 < nd) ? B.rec[begin + je0] : 0ull;
                const unsigned long long r1 = (je1 < nd) ? B.rec[begin + je1] : 0ull;
                const unsigned s0 = (unsigned)r0 & 0x1FFFFu;
                const unsigned s1 = (unsigned)r1 & 0x1FFFFu;
                const float w0 = __uint_as_float(
                    ((((unsigned)(r0 >> sh)) & 0x7FFu) + 7168u) << 17);
                const float w1 = __uint_as_float(
                    ((((unsigned)(r1 >> sh)) & 0x7FFu) + 7168u) << 17);
                const uint2 zv0 = *(const uint2*)(zb + ((size_t)s0 << 6));
                const uint2 zv1 = *(const uint2*)(zb + ((size_t)s1 << 6));
                a0 = fmaf(w0, __uint_as_float(zv0.x << 16), a0);
                a1 = fmaf(w0, __uint_as_float(zv0.x & 0xFFFF0000u), a1);
                a2 = fmaf(w0, __uint_as_float(zv0.y << 16), a2);
                a3 = fmaf(w0, __uint_as_float(zv0.y & 0xFFFF0000u), a3);
                den += w0;
                a0 = fmaf(w1, __uint_as_float(zv1.x << 16), a0);
                a1 = fmaf(w1, __uint_as_float(zv1.x & 0xFFFF0000u), a1);
                a2 = fmaf(w1, __uint_as_float(zv1.y << 16), a2);
                a3 = fmaf(w1, __uint_as_float(zv1.y & 0xFFFF0000u), a3);
                den += w1;
            }
            a0 += __shfl_xor(a0, 16); a0 += __shfl_xor(a0, 32);
            a1 += __shfl_xor(a1, 16); a1 += __shfl_xor(a1, 32);
            a2 += __shfl_xor(a2, 16); a2 += __shfl_xor(a2, 32);
            a3 += __shfl_xor(a3, 16); a3 += __shfl_xor(a3, 32);
            den += __shfl_xor(den, 16); den += __shfl_xor(den, 32);
            if (lane < 16 && d < NV) {
                const float id = 1.f / (den + 1e-9f);
                float v0 = a0 * id, v1 = a1 * id, v2 = a2 * id, v3 = a3 * id;
                v0 = v0 > 0.f ? v0 : __expf(v0) - 1.f;
                v1 = v1 > 0.f ? v1 : __expf(v1) - 1.f;
                v2 = v2 > 0.f ? v2 : __expf(v2) - 1.f;
                v3 = v3 > 0.f ? v3 : __expf(v3) - 1.f;
                *(float4*)(out + (size_t)d * NF + li * 4) =
                    make_float4(v0, v1, v2, v3);
            }
        }
    }
}

extern "C" void kernel_launch(void* const* d_in, const int* in_sizes, int n_in,
                              void* d_out, int out_size, void* d_ws, size_t ws_size,
                              hipStream_t stream)
{
    const float* x     = (const float*)d_in[0];
    const int*   ei    = (const int*)d_in[1];
    const float* W     = (const float*)d_in[2];
    const float* a_src = (const float*)d_in[3];
    const float* a_dst = (const float*)d_in[4];
    float* out = (float*)d_out;

    // workspace layout (~23.7 MB)
    char* p = (char*)d_ws;
    __hip_bfloat16* z = (__hip_bfloat16*)p;  p += (size_t)NV * NF * 2;      // 12.8 MB
    float* esrc = (float*)p;                 p += (size_t)NV * NH * 4;      // 1.6 MB
    float* edst = (float*)p;                 p += (size_t)NV * NH * 4;      // 1.6 MB
    int*   gcur = (int*)p;                   p += (size_t)NBKT * 4;
    p = (char*)(((uintptr_t)p + 255) & ~(uintptr_t)255);
    short* wfrag = (short*)p;                p += (size_t)1280 * 8 * 2;     // 20 KB
    p = (char*)(((uintptr_t)p + 255) & ~(uintptr_t)255);
    unsigned* barr = (unsigned*)p;           p += (size_t)NBKT * BCAP * 4;  // 7.6 MB

    // size the cooperative grid from measured occupancy (never oversubscribe)
    static int nb = -1;
    if (nb < 0) {
        if (hipOccupancyMaxActiveBlocksPerMultiprocessor(&nb, k_fused, 256, 0)
                != hipSuccess || nb <= 0)
            nb = 4;
        if (nb > 8) nb = 8;   // 32-wave/CU cap with 4-wave blocks
    }
    int gridn = nb * 256;     // MI355X: 256 CUs
    if (gridn > NITEMS) gridn = NITEMS;

    void* args[] = { (void*)&x, (void*)&ei, (void*)&W, (void*)&a_src,
                     (void*)&a_dst, (void*)&z, (void*)&esrc, (void*)&edst,
                     (void*)&gcur, (void*)&wfrag, (void*)&barr, (void*)&out };
    hipLaunchCooperativeKernel((const void*)k_fused, dim3(gridn), dim3(256),
                               args, 0, stream);
}

// Round 6
// 458.297 us; speedup vs baseline: 1.3461x; 1.3461x over previous
//
#include <hip/hip_runtime.h>
#include <hip/hip_bf16.h>
#include <hip/hip_cooperative_groups.h>
#include <cstdint>

namespace cg = cooperative_groups;

#define NV 100000
#define NE 1600000
#define KIN 128
#define NH 4
#define NC 16
#define NF 64      // NH*NC
#define NBKT 1563  // ceil(NV/64) buckets of 64 dsts
#define BCAP 1216  // mean fill 1024, sd ~32 -> +6 sigma safe (fixed dataset)
#define EPW 16     // edges per thread in bin body (256 thr -> 4096 edges/item)
#define BINWG 391  // ceil(NE / (256*EPW))
#define GEMMWG 1563 // ceil(NV/64), 64 rows per gemm item
#define NITEMS 1954 // BINWG + GEMMWG, interleaved %5
#define XSTR 136   // LDS row stride in bf16 (272 B: b128-aligned, bank-uniform)

typedef __attribute__((ext_vector_type(8))) short bf16x8;
typedef __attribute__((ext_vector_type(4))) float f32x4;

// LDS union at FILE scope: per-block LDS with compiler-known addrspace, so
// noinline phase functions keep ds_-addressing and DS atomics (a kernel-local
// __shared__ passed by pointer would decay to flat access across the call).
union SMU {
    struct { int hist[NBKT]; int base[NBKT]; } bin;            // 12504 B
    short xs[64 * XSTR];                                       // 17408 B
    struct {
        unsigned arr[BCAP];            // 4864
        unsigned long long rec[BCAP];  // 9728
        int hist[64], off[64], cur[64];
        float4 led[64];                // -> total 16384 B
    } back;
};
__shared__ SMU sm;

__device__ __forceinline__ short f2bf(float f) {   // RNE bf16
    unsigned u = __float_as_uint(f);
    return (short)((u + 0x7FFFu + ((u >> 16) & 1u)) >> 16);
}

// 11-bit positive-float weight codec: e5m6, bias field 7168=(112<<6).
// Covers w in [2^-15, 2^16]; rel err <= 2^-7 RNE.
__device__ __forceinline__ unsigned enc11(float w) {
    unsigned t = (__float_as_uint(w) + 0x10000u) >> 17;
    t = min(max(t, 7168u), 9215u);
    return t - 7168u;
}

// ---- P0: zero gcur, build wfrag (incl. folded logit columns ct=4) ----
__attribute__((noinline)) __device__ void phase_prep(
    const float* __restrict__ W, const float* __restrict__ a_src,
    const float* __restrict__ a_dst, short* __restrict__ wfrag,
    int* __restrict__ gcur, int gtid, int gth)
{
    for (int i = gtid; i < NBKT; i += gth) gcur[i] = 0;
    for (int g = gtid; g < 1280; g += gth) {
        const int lane = g & 63;
        const int ctks = g >> 6;               // 0..19
        const int ct = ctks >> 2, ks = ctks & 3;
        const int n = lane & 15, quad = lane >> 4;
        short* dst = wfrag + (size_t)g * 8;
#pragma unroll
        for (int j = 0; j < 8; ++j) {
            const int k = ks * 32 + quad * 8 + j;
            float v = 0.f;
            if (ct < 4) {
                v = W[k * NF + ct * 16 + n];
            } else if (n < 8) {
                const int h = n & 3;
                const float* __restrict__ a =
                    (n < 4) ? (a_src + h * 16) : (a_dst + h * 16);
                for (int c = 0; c < 16; ++c)
                    v += W[k * NF + h * 16 + c] * a[c];
            }
            dst[j] = f2bf(v);
        }
    }
}

// ---- P1a: bin item ib — bucket edges by dst>>6, item=(dlocal<<17)|src ----
__attribute__((noinline)) __device__ void phase_bin(
    const int* __restrict__ ei, int* __restrict__ gcur,
    unsigned* __restrict__ barr, int ib)
{
    int* hist = sm.bin.hist;
    int* base = sm.bin.base;
    const int t = threadIdx.x;
    const int e0 = ib * (256 * EPW);

    for (int i = t; i < NBKT; i += 256) hist[i] = 0;
    __syncthreads();

    unsigned pk[EPW];
    short bk[EPW];
#pragma unroll
    for (int i = 0; i < EPW; ++i) {
        const int e = e0 + i * 256 + t;
        if (e < NE) {
            const int s = ei[e];
            const int d = ei[NE + e];
            const int bkt = d >> 6;
            bk[i] = (short)bkt;
            pk[i] = ((unsigned)(d & 63) << 17) | (unsigned)s;
            atomicAdd(&hist[bkt], 1);
        } else {
            bk[i] = -1;
        }
    }
    __syncthreads();
    for (int i = t; i < NBKT; i += 256) {
        const int c = hist[i];
        base[i] = c ? atomicAdd(&gcur[i], c) : 0;
        hist[i] = 0;   // reuse as local cursor
    }
    __syncthreads();
#pragma unroll
    for (int i = 0; i < EPW; ++i) {
        if (bk[i] >= 0) {
            const int bkt = bk[i];
            const int pos = base[bkt] + atomicAdd(&hist[bkt], 1);
            if (pos < BCAP)
                barr[(size_t)bkt * BCAP + pos] = pk[i];
        }
    }
}

// ---- P1b: gemm item idg — [z | logits] = x @ [W | Wa], 64 rows ----
__attribute__((noinline)) __device__ void phase_gemm(
    const float* __restrict__ x, const short* __restrict__ wfrag,
    __hip_bfloat16* __restrict__ z, float* __restrict__ esrc,
    float* __restrict__ edst, int idg)
{
    short* xs = sm.xs;
    const int t = threadIdx.x;
    const float4* __restrict__ x4 = (const float4*)x;

#pragma unroll
    for (int i = 0; i < 8; ++i) {
        const int li = i * 256 + t;
        const int idx = idg * 2048 + li;
        float4 v = make_float4(0.f, 0.f, 0.f, 0.f);
        if (idx < NV * (KIN / 4)) v = x4[idx];
        const unsigned lo = (unsigned)(unsigned short)f2bf(v.x)
                          | ((unsigned)(unsigned short)f2bf(v.y) << 16);
        const unsigned hi = (unsigned)(unsigned short)f2bf(v.z)
                          | ((unsigned)(unsigned short)f2bf(v.w) << 16);
        *(uint2*)&xs[(li >> 5) * XSTR + (li & 31) * 4] = make_uint2(lo, hi);
    }
    __syncthreads();

    const int wv = t >> 6;
    const int lane = t & 63;
    const int n = lane & 15;
    const int quad = lane >> 4;

    const bf16x8* __restrict__ wf = (const bf16x8*)wfrag;
    const short* __restrict__ arow = &xs[(wv * 16 + n) * XSTR];
    f32x4 acc[5];
#pragma unroll
    for (int ct = 0; ct < 5; ++ct) acc[ct] = (f32x4){0.f, 0.f, 0.f, 0.f};

#pragma unroll
    for (int ks = 0; ks < 4; ++ks) {
        const bf16x8 af = *(const bf16x8*)(arow + ks * 32 + quad * 8);
#pragma unroll
        for (int ct = 0; ct < 5; ++ct)
            acc[ct] = __builtin_amdgcn_mfma_f32_16x16x32_bf16(
                af, wf[(ct * 4 + ks) * 64 + lane], acc[ct], 0, 0, 0);
    }

    unsigned short* __restrict__ zz = (unsigned short*)z;
#pragma unroll
    for (int ct = 0; ct < 4; ++ct) {
#pragma unroll
        for (int reg = 0; reg < 4; ++reg) {
            const int r_g = idg * 64 + wv * 16 + quad * 4 + reg;
            if (r_g < NV)
                zz[(size_t)r_g * NF + ct * 16 + n] =
                    (unsigned short)f2bf(acc[ct][reg]);
        }
    }
#pragma unroll
    for (int reg = 0; reg < 4; ++reg) {
        const int r_g = idg * 64 + wv * 16 + quad * 4 + reg;
        if (r_g < NV && n < 8) {
            const float v = acc[4][reg];
            if (n < 4) esrc[r_g * NH + n] = v;
            else       edst[r_g * NH + (n - 4)] = v;
        }
    }
}

// ---- P2: bucket b — fused CSR-build + aggregation ----
__attribute__((noinline)) __device__ void phase_back(
    const int* __restrict__ gcur, const unsigned* __restrict__ barr,
    const float* __restrict__ esrc, const float* __restrict__ edst,
    const __hip_bfloat16* __restrict__ z, float* __restrict__ out, int b)
{
    auto& B = sm.back;
    const int t = threadIdx.x;
    int f = gcur[b]; if (f > BCAP) f = BCAP;
    const unsigned* __restrict__ bp = barr + (size_t)b * BCAP;

    if (t < 64) {
        B.hist[t] = 0;
        B.cur[t] = 0;
        const int d = b * 64 + t;
        B.led[t] = (d < NV) ? *(const float4*)(edst + (size_t)d * 4)
                            : make_float4(0.f, 0.f, 0.f, 0.f);
    }
    __syncthreads();
    const int f4 = f >> 2;
    for (int i = t; i < f4; i += 256) {
        const uint4 v = ((const uint4*)bp)[i];
        ((uint4*)B.arr)[i] = v;
        atomicAdd(&B.hist[v.x >> 17], 1);
        atomicAdd(&B.hist[v.y >> 17], 1);
        atomicAdd(&B.hist[v.z >> 17], 1);
        atomicAdd(&B.hist[v.w >> 17], 1);
    }
    for (int i = (f4 << 2) + t; i < f; i += 256) {
        const unsigned v = bp[i];
        B.arr[i] = v;
        atomicAdd(&B.hist[v >> 17], 1);
    }
    __syncthreads();
    if (t < 64) B.off[t] = B.hist[t];
    __syncthreads();
    for (int s = 1; s < 64; s <<= 1) {
        const int v = (t < 64 && t >= s) ? B.off[t - s] : 0;
        __syncthreads();
        if (t < 64) B.off[t] += v;
        __syncthreads();
    }
    if (t < 64) B.off[t] -= B.hist[t];   // exclusive
    __syncthreads();

    // build sorted weight records in LDS
    for (int i = t; i < f; i += 256) {
        const unsigned p = B.arr[i];
        const int dl = p >> 17;
        const unsigned s = p & 0x1FFFFu;
        const int slot = B.off[dl] + atomicAdd(&B.cur[dl], 1);
        const float4 e4 = *(const float4*)(esrc + (size_t)s * 4);
        const float4 ed = B.led[dl];
        float ev;
        ev = e4.x + ed.x; ev = ev > 0.f ? ev : 0.2f * ev;
        const unsigned w0 = enc11(__expf(ev));
        ev = e4.y + ed.y; ev = ev > 0.f ? ev : 0.2f * ev;
        const unsigned w1 = enc11(__expf(ev));
        ev = e4.z + ed.z; ev = ev > 0.f ? ev : 0.2f * ev;
        const unsigned w2 = enc11(__expf(ev));
        ev = e4.w + ed.w; ev = ev > 0.f ? ev : 0.2f * ev;
        const unsigned w3 = enc11(__expf(ev));
        B.rec[slot] = (unsigned long long)s
            | ((unsigned long long)w0 << 17)
            | ((unsigned long long)w1 << 28)
            | ((unsigned long long)w2 << 39)
            | ((unsigned long long)w3 << 50);
    }
    __syncthreads();

    // aggregation: wave wv handles dls with (dl&3)==wv; 8 edges per iter
    const int wv = t >> 6;
    const int lane = t & 63;
    const int quad = lane >> 4;          // edge slot within group
    const int li = lane & 15;            // channel-quad: chans 4li..4li+3
    const int sh = 17 + 11 * (li >> 2);  // this lane's head weight field
    const unsigned short* __restrict__ zb = (const unsigned short*)z + li * 4;

    for (int k = 0; k < 16; ++k) {
        const int dl = (k << 2) | wv;
        const int d = b * 64 + dl;
        const int begin = B.off[dl];
        const int nd = B.hist[dl];
        float a0 = 0.f, a1 = 0.f, a2 = 0.f, a3 = 0.f, den = 0.f;
        for (int j = 0; j < nd; j += 8) {
            const int je0 = j + quad;
            const int je1 = je0 + 4;
            const unsigned long long r0 = (je0 < nd) ? B.rec[begin + je0] : 0ull;
            const unsigned long long r1 = (je1 < nd) ? B.rec[begin + je1] : 0ull;
            const unsigned s0 = (unsigned)r0 & 0x1FFFFu;
            const unsigned s1 = (unsigned)r1 & 0x1FFFFu;
            const float w0 = __uint_as_float(
                ((((unsigned)(r0 >> sh)) & 0x7FFu) + 7168u) << 17);
            const float w1 = __uint_as_float(
                ((((unsigned)(r1 >> sh)) & 0x7FFu) + 7168u) << 17);
            const uint2 zv0 = *(const uint2*)(zb + ((size_t)s0 << 6));
            const uint2 zv1 = *(const uint2*)(zb + ((size_t)s1 << 6));
            a0 = fmaf(w0, __uint_as_float(zv0.x << 16), a0);
            a1 = fmaf(w0, __uint_as_float(zv0.x & 0xFFFF0000u), a1);
            a2 = fmaf(w0, __uint_as_float(zv0.y << 16), a2);
            a3 = fmaf(w0, __uint_as_float(zv0.y & 0xFFFF0000u), a3);
            den += w0;
            a0 = fmaf(w1, __uint_as_float(zv1.x << 16), a0);
            a1 = fmaf(w1, __uint_as_float(zv1.x & 0xFFFF0000u), a1);
            a2 = fmaf(w1, __uint_as_float(zv1.y << 16), a2);
            a3 = fmaf(w1, __uint_as_float(zv1.y & 0xFFFF0000u), a3);
            den += w1;
        }
        a0 += __shfl_xor(a0, 16); a0 += __shfl_xor(a0, 32);
        a1 += __shfl_xor(a1, 16); a1 += __shfl_xor(a1, 32);
        a2 += __shfl_xor(a2, 16); a2 += __shfl_xor(a2, 32);
        a3 += __shfl_xor(a3, 16); a3 += __shfl_xor(a3, 32);
        den += __shfl_xor(den, 16); den += __shfl_xor(den, 32);
        if (lane < 16 && d < NV) {
            const float id = 1.f / (den + 1e-9f);
            float v0 = a0 * id, v1 = a1 * id, v2 = a2 * id, v3 = a3 * id;
            v0 = v0 > 0.f ? v0 : __expf(v0) - 1.f;
            v1 = v1 > 0.f ? v1 : __expf(v1) - 1.f;
            v2 = v2 > 0.f ? v2 : __expf(v2) - 1.f;
            v3 = v3 > 0.f ? v3 : __expf(v3) - 1.f;
            *(float4*)(out + (size_t)d * NF + li * 4) =
                make_float4(v0, v1, v2, v3);
        }
    }
}

// ONE cooperative kernel, phases in noinline functions so register
// allocation is per-phase (round-4: joint alloc -> 84 VGPR, occupancy
// collapse; round-5: (256,8) cap -> 32 VGPR + scratch spills, WRITE_SIZE
// +78MB). Standalone phases compiled to 36/24 VGPR; per-function isolation
// should restore that, giving 8 blk/CU with no spill.
__global__ __launch_bounds__(256) void k_fused(
    const float* __restrict__ x, const int* __restrict__ ei,
    const float* __restrict__ W, const float* __restrict__ a_src,
    const float* __restrict__ a_dst,
    __hip_bfloat16* __restrict__ z, float* __restrict__ esrc,
    float* __restrict__ edst, int* __restrict__ gcur,
    short* __restrict__ wfrag, unsigned* __restrict__ barr,
    float* __restrict__ out)
{
    cg::grid_group grid = cg::this_grid();
    const int bid = blockIdx.x;
    const int gsz = gridDim.x;

    phase_prep(W, a_src, a_dst, wfrag, gcur,
               bid * 256 + threadIdx.x, gsz * 256);
    __threadfence();
    grid.sync();

    for (int it = bid; it < NITEMS; it += gsz) {
        __syncthreads();   // LDS union reuse across items
        if (it % 5 == 0) phase_bin(ei, gcur, barr, it / 5);
        else             phase_gemm(x, wfrag, z, esrc, edst, it - it / 5 - 1);
    }
    __threadfence();
    grid.sync();

    for (int b = bid; b < NBKT; b += gsz) {
        __syncthreads();   // LDS union reuse across buckets
        phase_back(gcur, barr, esrc, edst, z, out, b);
    }
}

extern "C" void kernel_launch(void* const* d_in, const int* in_sizes, int n_in,
                              void* d_out, int out_size, void* d_ws, size_t ws_size,
                              hipStream_t stream)
{
    const float* x     = (const float*)d_in[0];
    const int*   ei    = (const int*)d_in[1];
    const float* W     = (const float*)d_in[2];
    const float* a_src = (const float*)d_in[3];
    const float* a_dst = (const float*)d_in[4];
    float* out = (float*)d_out;

    // workspace layout (~23.7 MB)
    char* p = (char*)d_ws;
    __hip_bfloat16* z = (__hip_bfloat16*)p;  p += (size_t)NV * NF * 2;      // 12.8 MB
    float* esrc = (float*)p;                 p += (size_t)NV * NH * 4;      // 1.6 MB
    float* edst = (float*)p;                 p += (size_t)NV * NH * 4;      // 1.6 MB
    int*   gcur = (int*)p;                   p += (size_t)NBKT * 4;
    p = (char*)(((uintptr_t)p + 255) & ~(uintptr_t)255);
    short* wfrag = (short*)p;                p += (size_t)1280 * 8 * 2;     // 20 KB
    p = (char*)(((uintptr_t)p + 255) & ~(uintptr_t)255);
    unsigned* barr = (unsigned*)p;           p += (size_t)NBKT * BCAP * 4;  // 7.6 MB

    // size the cooperative grid from measured occupancy (never oversubscribe)
    static int nb = -1;
    if (nb < 0) {
        if (hipOccupancyMaxActiveBlocksPerMultiprocessor(&nb, k_fused, 256, 0)
                != hipSuccess || nb <= 0)
            nb = 4;
        if (nb > 8) nb = 8;   // 32-wave/CU cap with 4-wave blocks
    }
    int gridn = nb * 256;     // MI355X: 256 CUs
    if (gridn > NITEMS) gridn = NITEMS;

    void* args[] = { (void*)&x, (void*)&ei, (void*)&W, (void*)&a_src,
                     (void*)&a_dst, (void*)&z, (void*)&esrc, (void*)&edst,
                     (void*)&gcur, (void*)&wfrag, (void*)&barr, (void*)&out };
    hipLaunchCooperativeKernel((const void*)k_fused, dim3(gridn), dim3(256),
                               args, 0, stream);
}

// Round 7
// 180.690 us; speedup vs baseline: 3.4141x; 2.5364x over previous
//
#include <hip/hip_runtime.h>
#include <hip/hip_bf16.h>
#include <cstdint>

#define NV 100000
#define NE 1600000
#define KIN 128
#define NH 4
#define NC 16
#define NF 64      // NH*NC
#define NBKT 1563  // ceil(NV/64) buckets of 64 dsts
#define BCAP 1216  // mean fill 1024, sd ~32 -> +6 sigma safe (fixed dataset)
#define EPW 16     // edges per thread in bin body (512 thr -> 8192 edges/item)
#define BINWG 196  // ceil(NE / (512*EPW))  -> halves gcur atomic volume
#define GEMMWG 782 // ceil(NV/128), 128 rows per 512-thread block
#define NITEMS 978 // BINWG + GEMMWG, bins interleaved %5
#define XSTR 136   // LDS row stride in bf16 (272 B: b128-aligned, bank-uniform)

typedef __attribute__((ext_vector_type(8))) short bf16x8;
typedef __attribute__((ext_vector_type(4))) float f32x4;

__device__ __forceinline__ short f2bf(float f) {   // RNE bf16
    unsigned u = __float_as_uint(f);
    return (short)((u + 0x7FFFu + ((u >> 16) & 1u)) >> 16);
}

// 11-bit positive-float weight codec: e5m6, bias field 7168=(112<<6).
// Covers w in [2^-15, 2^16]; rel err <= 2^-7 RNE.
__device__ __forceinline__ unsigned enc11(float w) {
    unsigned t = (__float_as_uint(w) + 0x10000u) >> 17;
    t = min(max(t, 7168u), 9215u);
    return t - 7168u;
}

// K1 "front": edge-binning + MFMA gemm, 512 threads. No k_prep dispatch:
// gcur is zeroed by a hipMemsetAsync node (cheap SDMA predecessor) and each
// gemm block builds its own W fragments from global W (L2-hot, 32 KB).
// Bin blocks process 8192 edges each (196 blocks): halves the returning
// device-atomic volume on gcur, the presumed k_front straggler.
__global__ __launch_bounds__(512) void k_front(
    const float* __restrict__ x, const float* __restrict__ W,
    const float* __restrict__ a_src, const float* __restrict__ a_dst,
    __hip_bfloat16* __restrict__ z, float* __restrict__ esrc,
    float* __restrict__ edst,
    const int* __restrict__ ei, int* __restrict__ gcur,
    unsigned* __restrict__ barr)
{
    __shared__ union SM {
        struct { int hist[NBKT]; int base[NBKT]; } bin;   // 12.5 KB
        short xs[128 * XSTR];                             // 34.8 KB
    } sm;

    const int bi = blockIdx.x;
    const int t = threadIdx.x;

    if (bi % 5 == 0) {
        // ---- bin body: bucket edges by dst>>6, item = (dlocal<<17)|src ----
        int* hist = sm.bin.hist;
        int* base = sm.bin.base;
        const int e0 = (bi / 5) * (512 * EPW);

        for (int i = t; i < NBKT; i += 512) hist[i] = 0;
        __syncthreads();

        unsigned pk[EPW];
        short bk[EPW];
#pragma unroll
        for (int i = 0; i < EPW; ++i) {
            const int e = e0 + i * 512 + t;
            if (e < NE) {
                const int s = ei[e];
                const int d = ei[NE + e];
                const int bkt = d >> 6;
                bk[i] = (short)bkt;
                pk[i] = ((unsigned)(d & 63) << 17) | (unsigned)s;
                atomicAdd(&hist[bkt], 1);
            } else {
                bk[i] = -1;
            }
        }
        __syncthreads();
        for (int i = t; i < NBKT; i += 512) {
            const int c = hist[i];
            base[i] = c ? atomicAdd(&gcur[i], c) : 0;
            hist[i] = 0;   // reuse as local cursor
        }
        __syncthreads();
#pragma unroll
        for (int i = 0; i < EPW; ++i) {
            if (bk[i] >= 0) {
                const int bkt = bk[i];
                const int pos = base[bkt] + atomicAdd(&hist[bkt], 1);
                if (pos < BCAP)
                    barr[(size_t)bkt * BCAP + pos] = pk[i];
            }
        }
    } else {
        // ---- gemm body: z = x @ W (bf16 MFMA, 128 rows) + shuffle logits ----
        short* xs = sm.xs;
        const int id = bi - bi / 5 - 1;   // 0..GEMMWG-1
        const float4* __restrict__ x4 = (const float4*)x;

#pragma unroll
        for (int i = 0; i < 8; ++i) {
            const int li = i * 512 + t;
            const int idx = id * 4096 + li;
            float4 v = make_float4(0.f, 0.f, 0.f, 0.f);
            if (idx < NV * (KIN / 4)) v = x4[idx];
            const unsigned lo = (unsigned)(unsigned short)f2bf(v.x)
                              | ((unsigned)(unsigned short)f2bf(v.y) << 16);
            const unsigned hi = (unsigned)(unsigned short)f2bf(v.z)
                              | ((unsigned)(unsigned short)f2bf(v.w) << 16);
            *(uint2*)&xs[(li >> 5) * XSTR + (li & 31) * 4] = make_uint2(lo, hi);
        }
        __syncthreads();

        const int wv = t >> 6;               // 0..7 -> rows wv*16..wv*16+15
        const int lane = t & 63;
        const int n = lane & 15;
        const int quad = lane >> 4;

        // self-build the 16 B-fragments from W (coalesced across the 16
        // n-lanes; W is L2-resident after first touch)
        bf16x8 bf[16];
#pragma unroll
        for (int ct = 0; ct < 4; ++ct) {
#pragma unroll
            for (int ks = 0; ks < 4; ++ks) {
                bf16x8 f;
#pragma unroll
                for (int j = 0; j < 8; ++j) {
                    const int k = ks * 32 + quad * 8 + j;
                    f[j] = f2bf(W[k * NF + ct * 16 + n]);
                }
                bf[ct * 4 + ks] = f;
            }
        }

        const short* __restrict__ arow = &xs[(wv * 16 + n) * XSTR];
        f32x4 acc[4];
#pragma unroll
        for (int ct = 0; ct < 4; ++ct) acc[ct] = (f32x4){0.f, 0.f, 0.f, 0.f};

#pragma unroll
        for (int ks = 0; ks < 4; ++ks) {
            const bf16x8 af = *(const bf16x8*)(arow + ks * 32 + quad * 8);
#pragma unroll
            for (int ct = 0; ct < 4; ++ct)
                acc[ct] = __builtin_amdgcn_mfma_f32_16x16x32_bf16(
                    af, bf[ct * 4 + ks], acc[ct], 0, 0, 0);
        }

        float as[4], ad[4];
#pragma unroll
        for (int ct = 0; ct < 4; ++ct) {
            as[ct] = a_src[ct * 16 + n];
            ad[ct] = a_dst[ct * 16 + n];
        }
        unsigned short* __restrict__ zz = (unsigned short*)z;
#pragma unroll
        for (int ct = 0; ct < 4; ++ct) {
#pragma unroll
            for (int reg = 0; reg < 4; ++reg) {
                const int r_g = id * 128 + wv * 16 + quad * 4 + reg;
                const float v = acc[ct][reg];
                float ps = v * as[ct];
                float pd = v * ad[ct];
#pragma unroll
                for (int m = 8; m >= 1; m >>= 1) {
                    ps += __shfl_xor(ps, m, 16);
                    pd += __shfl_xor(pd, m, 16);
                }
                if (r_g < NV) {
                    zz[(size_t)r_g * NF + ct * 16 + n] = (unsigned short)f2bf(v);
                    if (n == 0) {
                        esrc[r_g * NH + ct] = ps;
                        edst[r_g * NH + ct] = pd;
                    }
                }
            }
        }
    }
}

// K2 "back": fused CSR-build + aggregation. One 256-thread wg per 64-dst
// bucket (proven round-3 shape, 51 us). Stage arr (uint4) fused with
// histogram; scan; build e5m6 weight records into LDS; agg with 2-deep ILP.
__global__ __launch_bounds__(256) void k_back(
    const int* __restrict__ gcur, const unsigned* __restrict__ barr,
    const float* __restrict__ esrc, const float* __restrict__ edst,
    const __hip_bfloat16* __restrict__ z, float* __restrict__ out)
{
    __shared__ __align__(16) unsigned arr[BCAP];   // 4864 B
    __shared__ unsigned long long rec[BCAP];       // 9728 B
    __shared__ int hist[64], off[64], cur[64];
    __shared__ float4 led[64];                     // total = 16384 B
    const int t = threadIdx.x;
    const int b = blockIdx.x;
    int f = gcur[b]; if (f > BCAP) f = BCAP;
    const unsigned* __restrict__ bp = barr + (size_t)b * BCAP;

    if (t < 64) {
        hist[t] = 0;
        cur[t] = 0;
        const int d = b * 64 + t;
        led[t] = (d < NV) ? *(const float4*)(edst + (size_t)d * 4)
                          : make_float4(0.f, 0.f, 0.f, 0.f);
    }
    __syncthreads();
    const int f4 = f >> 2;
    for (int i = t; i < f4; i += 256) {
        const uint4 v = ((const uint4*)bp)[i];
        ((uint4*)arr)[i] = v;
        atomicAdd(&hist[v.x >> 17], 1);
        atomicAdd(&hist[v.y >> 17], 1);
        atomicAdd(&hist[v.z >> 17], 1);
        atomicAdd(&hist[v.w >> 17], 1);
    }
    for (int i = (f4 << 2) + t; i < f; i += 256) {
        const unsigned v = bp[i];
        arr[i] = v;
        atomicAdd(&hist[v >> 17], 1);
    }
    __syncthreads();
    if (t < 64) off[t] = hist[t];
    __syncthreads();
    for (int s = 1; s < 64; s <<= 1) {
        const int v = (t < 64 && t >= s) ? off[t - s] : 0;
        __syncthreads();
        if (t < 64) off[t] += v;
        __syncthreads();
    }
    if (t < 64) off[t] -= hist[t];   // exclusive
    __syncthreads();

    // build sorted weight records in LDS
    for (int i = t; i < f; i += 256) {
        const unsigned p = arr[i];
        const int dl = p >> 17;
        const unsigned s = p & 0x1FFFFu;
        const int slot = off[dl] + atomicAdd(&cur[dl], 1);
        const float4 e4 = *(const float4*)(esrc + (size_t)s * 4);
        const float4 ed = led[dl];
        float ev;
        ev = e4.x + ed.x; ev = ev > 0.f ? ev : 0.2f * ev;
        const unsigned w0 = enc11(__expf(ev));
        ev = e4.y + ed.y; ev = ev > 0.f ? ev : 0.2f * ev;
        const unsigned w1 = enc11(__expf(ev));
        ev = e4.z + ed.z; ev = ev > 0.f ? ev : 0.2f * ev;
        const unsigned w2 = enc11(__expf(ev));
        ev = e4.w + ed.w; ev = ev > 0.f ? ev : 0.2f * ev;
        const unsigned w3 = enc11(__expf(ev));
        rec[slot] = (unsigned long long)s
            | ((unsigned long long)w0 << 17)
            | ((unsigned long long)w1 << 28)
            | ((unsigned long long)w2 << 39)
            | ((unsigned long long)w3 << 50);
    }
    __syncthreads();

    // aggregation: wave wv handles dls with (dl&3)==wv; 8 edges per iter
    const int wv = t >> 6;
    const int lane = t & 63;
    const int quad = lane >> 4;          // edge slot within group
    const int li = lane & 15;            // channel-quad: chans 4li..4li+3
    const int sh = 17 + 11 * (li >> 2);  // this lane's head weight field
    const unsigned short* __restrict__ zb = (const unsigned short*)z + li * 4;

    for (int k = 0; k < 16; ++k) {
        const int dl = (k << 2) | wv;
        const int d = b * 64 + dl;
        const int begin = off[dl];
        const int nd = hist[dl];
        float a0 = 0.f, a1 = 0.f, a2 = 0.f, a3 = 0.f, den = 0.f;
        for (int j = 0; j < nd; j += 8) {
            const int je0 = j + quad;
            const int je1 = je0 + 4;
            const unsigned long long r0 = (je0 < nd) ? rec[begin + je0] : 0ull;
            const unsigned long long r1 = (je1 < nd) ? rec[begin + je1] : 0ull;
            const unsigned s0 = (unsigned)r0 & 0x1FFFFu;
            const unsigned s1 = (unsigned)r1 & 0x1FFFFu;
            const float w0 = __uint_as_float(
                ((((unsigned)(r0 >> sh)) & 0x7FFu) + 7168u) << 17);
            const float w1 = __uint_as_float(
                ((((unsigned)(r1 >> sh)) & 0x7FFu) + 7168u) << 17);
            const uint2 zv0 = *(const uint2*)(zb + ((size_t)s0 << 6));
            const uint2 zv1 = *(const uint2*)(zb + ((size_t)s1 << 6));
            a0 = fmaf(w0, __uint_as_float(zv0.x << 16), a0);
            a1 = fmaf(w0, __uint_as_float(zv0.x & 0xFFFF0000u), a1);
            a2 = fmaf(w0, __uint_as_float(zv0.y << 16), a2);
            a3 = fmaf(w0, __uint_as_float(zv0.y & 0xFFFF0000u), a3);
            den += w0;
            a0 = fmaf(w1, __uint_as_float(zv1.x << 16), a0);
            a1 = fmaf(w1, __uint_as_float(zv1.x & 0xFFFF0000u), a1);
            a2 = fmaf(w1, __uint_as_float(zv1.y << 16), a2);
            a3 = fmaf(w1, __uint_as_float(zv1.y & 0xFFFF0000u), a3);
            den += w1;
        }
        a0 += __shfl_xor(a0, 16); a0 += __shfl_xor(a0, 32);
        a1 += __shfl_xor(a1, 16); a1 += __shfl_xor(a1, 32);
        a2 += __shfl_xor(a2, 16); a2 += __shfl_xor(a2, 32);
        a3 += __shfl_xor(a3, 16); a3 += __shfl_xor(a3, 32);
        den += __shfl_xor(den, 16); den += __shfl_xor(den, 32);
        if (lane < 16 && d < NV) {
            const float id = 1.f / (den + 1e-9f);
            float v0 = a0 * id, v1 = a1 * id, v2 = a2 * id, v3 = a3 * id;
            v0 = v0 > 0.f ? v0 : __expf(v0) - 1.f;
            v1 = v1 > 0.f ? v1 : __expf(v1) - 1.f;
            v2 = v2 > 0.f ? v2 : __expf(v2) - 1.f;
            v3 = v3 > 0.f ? v3 : __expf(v3) - 1.f;
            *(float4*)(out + (size_t)d * NF + li * 4) =
                make_float4(v0, v1, v2, v3);
        }
    }
}

extern "C" void kernel_launch(void* const* d_in, const int* in_sizes, int n_in,
                              void* d_out, int out_size, void* d_ws, size_t ws_size,
                              hipStream_t stream)
{
    const float* x     = (const float*)d_in[0];
    const int*   ei    = (const int*)d_in[1];
    const float* W     = (const float*)d_in[2];
    const float* a_src = (const float*)d_in[3];
    const float* a_dst = (const float*)d_in[4];
    float* out = (float*)d_out;

    // workspace layout (~23.7 MB)
    char* p = (char*)d_ws;
    __hip_bfloat16* z = (__hip_bfloat16*)p;  p += (size_t)NV * NF * 2;      // 12.8 MB
    float* esrc = (float*)p;                 p += (size_t)NV * NH * 4;      // 1.6 MB
    float* edst = (float*)p;                 p += (size_t)NV * NH * 4;      // 1.6 MB
    int*   gcur = (int*)p;                   p += (size_t)NBKT * 4;
    p = (char*)(((uintptr_t)p + 255) & ~(uintptr_t)255);
    unsigned* barr = (unsigned*)p;           p += (size_t)NBKT * BCAP * 4;  // 7.6 MB

    hipMemsetAsync(gcur, 0, (size_t)NBKT * 4, stream);
    k_front<<<NITEMS, 512, 0, stream>>>(x, W, a_src, a_dst, z, esrc, edst,
                                        ei, gcur, barr);
    k_back<<<NBKT, 256, 0, stream>>>(gcur, barr, esrc, edst, z, out);
}